// Round 2
// baseline (3645.481 us; speedup 1.0000x reference)
//
#include <hip/hip_runtime.h>
#include <hip/hip_bf16.h>

typedef __hip_bfloat16 bf16;
typedef __attribute__((ext_vector_type(8))) short short8;
typedef __attribute__((ext_vector_type(4))) float f32x4;

#define GLB_AS(p) ((const __attribute__((address_space(1))) void*)(p))
#define LDS_AS(p) ((__attribute__((address_space(3))) void*)(p))

// ---------------------------------------------------------------------------
// Generic batched bf16 MFMA GEMM: C[m,n] = sum_k A[m,k]*B[n,k]  (+ epilogue)
// Tile: BM=BN=128, BK=64. Block=256 threads (4 waves, 2x2 of 64x64).
// grid = (M/128, N/128, batches). All dims must divide evenly (they do here).
// epi: 0 = +bias -> f32 store; 1 = +bias -> bf16; 2 = +bias,GELU -> bf16;
//      3 = *scale + dist/causal mask -> bf16 (attention scores)
// ---------------------------------------------------------------------------
__global__ __launch_bounds__(256) void gemm_bf16(
    const bf16* __restrict__ Ain, const bf16* __restrict__ Bin, void* __restrict__ Cv,
    int K, int lda, int ldb, int ldc,
    long sAo, long sAi, long sBo, long sBi, long sCo, long sCi, int nInner,
    const float* __restrict__ bias, const float* __restrict__ demb,
    float scale, int epi)
{
    __shared__ __align__(16) bf16 Als[128 * 64];
    __shared__ __align__(16) bf16 Bls[128 * 64];

    const int z  = blockIdx.z;
    const int zo = z / nInner;
    const int zi = z - zo * nInner;
    const bf16* A = Ain + zo * sAo + zi * sAi;
    const bf16* B = Bin + zo * sBo + zi * sBi;
    const long coff = zo * sCo + zi * sCi;

    const int m0 = blockIdx.x * 128;
    const int n0 = blockIdx.y * 128;

    const int tid  = threadIdx.x;
    const int wave = tid >> 6;
    const int lane = tid & 63;
    const int wm = (wave >> 1) * 64;   // wave row offset in 128-tile
    const int wn = (wave & 1) * 64;    // wave col offset

    f32x4 acc[4][4];
#pragma unroll
    for (int i = 0; i < 4; ++i)
#pragma unroll
        for (int j = 0; j < 4; ++j) acc[i][j] = (f32x4){0.f, 0.f, 0.f, 0.f};

    // staging: each wave stages 4 chunks of 1KB for A and B.
    // chunk c = rows [c*8, c*8+8) x 64 cols. lane i -> row c*8+i/8, col (i%8)*8.
    const int srow = lane >> 3;        // 0..7
    const int scol = (lane & 7) << 3;  // 0,8,..,56

    for (int k0 = 0; k0 < K; k0 += 64) {
        __syncthreads();   // protect LDS from previous iteration's readers
#pragma unroll
        for (int c = 0; c < 4; ++c) {
            const int chunk = (wave << 2) + c;
            const int row = (chunk << 3) + srow;
            const bf16* ga = A + (long)(m0 + row) * lda + k0 + scol;
            const bf16* gb = B + (long)(n0 + row) * ldb + k0 + scol;
            __builtin_amdgcn_global_load_lds(GLB_AS(ga), LDS_AS(&Als[chunk << 9]), 16, 0, 0);
            __builtin_amdgcn_global_load_lds(GLB_AS(gb), LDS_AS(&Bls[chunk << 9]), 16, 0, 0);
        }
        __syncthreads();   // drain global_load_lds (vmcnt) + visibility

#pragma unroll
        for (int kk = 0; kk < 2; ++kk) {
            const int kof = (kk << 5) + ((lane >> 4) << 3);  // k offset in BK
            const int r = lane & 15;
            short8 afr[4], bfr[4];
#pragma unroll
            for (int i = 0; i < 4; ++i)
                afr[i] = *(const short8*)&Als[(wm + (i << 4) + r) * 64 + kof];
#pragma unroll
            for (int j = 0; j < 4; ++j)
                bfr[j] = *(const short8*)&Bls[(wn + (j << 4) + r) * 64 + kof];
#pragma unroll
            for (int i = 0; i < 4; ++i)
#pragma unroll
                for (int j = 0; j < 4; ++j)
                    acc[i][j] = __builtin_amdgcn_mfma_f32_16x16x32_bf16(
                        afr[i], bfr[j], acc[i][j], 0, 0, 0);
        }
    }

    // epilogue: C/D layout col=lane&15, row=(lane>>4)*4+reg
    const int ccol = lane & 15;
    const int crow = (lane >> 4) << 2;
#pragma unroll
    for (int i = 0; i < 4; ++i) {
#pragma unroll
        for (int j = 0; j < 4; ++j) {
            const int col  = n0 + wn + (j << 4) + ccol;
            const int rowb = m0 + wm + (i << 4) + crow;
#pragma unroll
            for (int r2 = 0; r2 < 4; ++r2) {
                const int row = rowb + r2;
                float v = acc[i][j][r2];
                const long cidx = coff + (long)row * ldc + col;
                if (epi == 3) {
                    // scores: row = query q, col = key k (within batch)
                    int d0 = row - col;
                    int ad = d0 < 0 ? -d0 : d0;
                    if (ad > 250) ad = 250;
                    const float mb = (col <= row) ? demb[ad * 8 + zi] : -1e9f;
                    ((bf16*)Cv)[cidx] = __float2bfloat16(v * scale + mb);
                } else if (epi == 0) {
                    if (bias) v += bias[col];
                    ((float*)Cv)[cidx] = v;
                } else if (epi == 1) {
                    if (bias) v += bias[col];
                    ((bf16*)Cv)[cidx] = __float2bfloat16(v);
                } else {
                    v += bias[col];
                    v = 0.5f * v * (1.0f + erff(v * 0.70710678118f));
                    ((bf16*)Cv)[cidx] = __float2bfloat16(v);
                }
            }
        }
    }
}

// ---------------------------------------------------------------------------
// fp32 -> bf16 cast (vectorized, n4 = count/4)
// ---------------------------------------------------------------------------
__global__ void cast_kernel(const float* __restrict__ in, bf16* __restrict__ out, long n4)
{
    long i = (long)blockIdx.x * blockDim.x + threadIdx.x;
    if (i < n4) {
        f32x4 v = *(const f32x4*)(in + i * 4);
        bf16 t[4] = {__float2bfloat16(v[0]), __float2bfloat16(v[1]),
                     __float2bfloat16(v[2]), __float2bfloat16(v[3])};
        *(short4*)(out + i * 4) = *(const short4*)t;
    }
}

// ---------------------------------------------------------------------------
// embedding: x[t,:] = token_emb[seq[t]] * 32  (sqrt(1024)); writes f32 + bf16
// grid = 8192 tokens, block = 256 (4 elems/thread)
// ---------------------------------------------------------------------------
__global__ void embed_kernel(const int* __restrict__ seq, const float* __restrict__ emb,
                             float* __restrict__ x, bf16* __restrict__ xb)
{
    const long t = blockIdx.x;
    const int tok = seq[t];
    const int tid = threadIdx.x;
    f32x4 v = *(const f32x4*)(emb + (long)tok * 1024 + tid * 4);
    v *= 32.0f;
    *(f32x4*)(x + t * 1024 + tid * 4) = v;
    bf16 tq[4] = {__float2bfloat16(v[0]), __float2bfloat16(v[1]),
                  __float2bfloat16(v[2]), __float2bfloat16(v[3])};
    *(short4*)(xb + t * 1024 + tid * 4) = *(const short4*)tq;
}

// ---------------------------------------------------------------------------
// softmax over rows of 256 (scores bf16 -> probs bf16). 1 wave/row, 4 rows/block.
// ---------------------------------------------------------------------------
__global__ void softmax_kernel(const bf16* __restrict__ scores, bf16* __restrict__ probs)
{
    const long row = (long)blockIdx.x * 4 + (threadIdx.x >> 6);
    const int lane = threadIdx.x & 63;
    short4 sv = *(const short4*)(scores + row * 256 + lane * 4);
    const bf16* sp = (const bf16*)&sv;
    float v0 = __bfloat162float(sp[0]), v1 = __bfloat162float(sp[1]);
    float v2 = __bfloat162float(sp[2]), v3 = __bfloat162float(sp[3]);
    float m = fmaxf(fmaxf(v0, v1), fmaxf(v2, v3));
#pragma unroll
    for (int off = 32; off; off >>= 1) m = fmaxf(m, __shfl_xor(m, off));
    float e0 = __expf(v0 - m), e1 = __expf(v1 - m);
    float e2 = __expf(v2 - m), e3 = __expf(v3 - m);
    float s = e0 + e1 + e2 + e3;
#pragma unroll
    for (int off = 32; off; off >>= 1) s += __shfl_xor(s, off);
    const float inv = 1.0f / s;
    bf16 tq[4] = {__float2bfloat16(e0 * inv), __float2bfloat16(e1 * inv),
                  __float2bfloat16(e2 * inv), __float2bfloat16(e3 * inv)};
    *(short4*)(probs + row * 256 + lane * 4) = *(const short4*)tq;
}

// ---------------------------------------------------------------------------
// V transpose: qkv[b,s,2E + h*128 + d] -> vt[b,h,d,s]  (bf16), LDS 32x33 tile
// grid = (32, 256): blockIdx.x = s-tile(8) | d-tile(4)<<3 ; blockIdx.y = b*8+h
// ---------------------------------------------------------------------------
__global__ void transpose_v(const bf16* __restrict__ qkv, bf16* __restrict__ vt)
{
    __shared__ bf16 tile[32][33];
    const int bh = blockIdx.y;
    const int st = blockIdx.x & 7;
    const int dt = blockIdx.x >> 3;
    const int tx = threadIdx.x & 31;
    const int ty = threadIdx.x >> 5;   // 0..7
    const int b = bh >> 3, h = bh & 7;
    const bf16* src = qkv + ((long)b * 256) * 3072 + 2048 + h * 128 + dt * 32;
#pragma unroll
    for (int i = 0; i < 4; ++i) {
        const int s = st * 32 + ty * 4 + i;
        tile[ty * 4 + i][tx] = src[(long)s * 3072 + tx];
    }
    __syncthreads();
    bf16* dst = vt + ((long)bh * 128 + dt * 32) * 256 + st * 32;
#pragma unroll
    for (int i = 0; i < 4; ++i) {
        const int dl = ty * 4 + i;
        dst[(long)dl * 256 + tx] = tile[tx][dl];
    }
}

// ---------------------------------------------------------------------------
// LayerNorm over E=1024: out = (x [+ res] - mean)/sqrt(var+1e-5)*g + b
// writes f32 (always) + bf16 (optional). grid = 8192 tokens, block = 256.
// ---------------------------------------------------------------------------
__global__ void ln_kernel(const float* __restrict__ x, const float* __restrict__ res,
                          const float* __restrict__ g, const float* __restrict__ bta,
                          float* __restrict__ outf, bf16* __restrict__ outb,
                          int has_res, int has_bf)
{
    const long t = blockIdx.x;
    const int tid = threadIdx.x;
    f32x4 v = *(const f32x4*)(x + t * 1024 + tid * 4);
    if (has_res) {
        f32x4 r = *(const f32x4*)(res + t * 1024 + tid * 4);
        v += r;
    }
    float s  = v[0] + v[1] + v[2] + v[3];
    float ss = v[0]*v[0] + v[1]*v[1] + v[2]*v[2] + v[3]*v[3];
#pragma unroll
    for (int off = 32; off; off >>= 1) {
        s  += __shfl_xor(s, off);
        ss += __shfl_xor(ss, off);
    }
    __shared__ float red[8];
    const int w = tid >> 6;
    if ((tid & 63) == 0) { red[w] = s; red[4 + w] = ss; }
    __syncthreads();
    s  = red[0] + red[1] + red[2] + red[3];
    ss = red[4] + red[5] + red[6] + red[7];
    const float mean = s * (1.0f / 1024.0f);
    const float var  = ss * (1.0f / 1024.0f) - mean * mean;
    const float rstd = rsqrtf(var + 1e-5f);
    f32x4 gv = *(const f32x4*)(g + tid * 4);
    f32x4 bv = *(const f32x4*)(bta + tid * 4);
    f32x4 o;
#pragma unroll
    for (int q = 0; q < 4; ++q) o[q] = (v[q] - mean) * rstd * gv[q] + bv[q];
    *(f32x4*)(outf + t * 1024 + tid * 4) = o;
    if (has_bf) {
        bf16 tq[4] = {__float2bfloat16(o[0]), __float2bfloat16(o[1]),
                      __float2bfloat16(o[2]), __float2bfloat16(o[3])};
        *(short4*)(outb + t * 1024 + tid * 4) = *(const short4*)tq;
    }
}

// ---------------------------------------------------------------------------
// logits: out[t,n] = xf[t,:].dot(W[n,:]) + b[n], N=45, K=1024 (fp32)
// 1 wave per token, 4 tokens/block. grid = 2048.
// ---------------------------------------------------------------------------
__global__ void gen_kernel(const float* __restrict__ xf, const float* __restrict__ W,
                           const float* __restrict__ bias, float* __restrict__ out)
{
    const long t = (long)blockIdx.x * 4 + (threadIdx.x >> 6);
    const int lane = threadIdx.x & 63;
    const float* xr = xf + t * 1024;
    float xv[16];
#pragma unroll
    for (int j = 0; j < 16; ++j) xv[j] = xr[lane + 64 * j];
    for (int n = 0; n < 45; ++n) {
        const float* wr = W + (long)n * 1024;
        float a = 0.f;
#pragma unroll
        for (int j = 0; j < 16; ++j) a += xv[j] * wr[lane + 64 * j];
#pragma unroll
        for (int off = 32; off; off >>= 1) a += __shfl_xor(a, off);
        if (lane == 0) out[t * 45 + n] = a + bias[n];
    }
}

// ---------------------------------------------------------------------------
extern "C" void kernel_launch(void* const* d_in, const int* in_sizes, int n_in,
                              void* d_out, int out_size, void* d_ws, size_t ws_size,
                              hipStream_t stream)
{
    (void)in_sizes; (void)n_in; (void)out_size; (void)ws_size;
    const int*   seq  = (const int*)d_in[0];
    const float* temb = (const float*)d_in[1];
    const float* demb = (const float*)d_in[2];
    const float* Wqkv = (const float*)d_in[3];
    const float* bqkv = (const float*)d_in[4];
    const float* Wo   = (const float*)d_in[5];
    const float* bo   = (const float*)d_in[6];
    const float* W1   = (const float*)d_in[7];
    const float* b1   = (const float*)d_in[8];
    const float* W2   = (const float*)d_in[9];
    const float* b2   = (const float*)d_in[10];
    const float* ln1g = (const float*)d_in[11];
    const float* ln1b = (const float*)d_in[12];
    const float* ln2g = (const float*)d_in[13];
    const float* ln2b = (const float*)d_in[14];
    const float* fng  = (const float*)d_in[15];
    const float* fnb  = (const float*)d_in[16];
    const float* genW = (const float*)d_in[17];
    const float* genb = (const float*)d_in[18];
    float* out = (float*)d_out;

    char* ws = (char*)d_ws;
    size_t off = 0;
    auto alloc = [&](size_t bytes) -> char* {
        char* p = ws + off;
        off += (bytes + 255) & ~(size_t)255;
        return p;
    };

    // Lifetime-aliased workspace (~226.5 MB total):
    bf16*  wqkv_l = (bf16*)alloc(3072ULL * 1024 * 2);    //  6.3 MB
    bf16*  wo_l   = (bf16*)alloc(1024ULL * 1024 * 2);    //  2.1 MB
    bf16*  w1_l   = (bf16*)alloc(4096ULL * 1024 * 2);    //  8.4 MB
    bf16*  w2_l   = (bf16*)alloc(1024ULL * 4096 * 2);    //  8.4 MB
    float* x      = (float*)alloc(8192ULL * 1024 * 4);   // 33.6 MB
    bf16*  xb     = (bf16*)alloc(8192ULL * 1024 * 2);    // 16.8 MB
    char*  qkvreg = alloc(8192ULL * 3072 * 2);           // 50.3 MB
    char*  R      = alloc(8192ULL * 4096 * 2);           // 67.1 MB
    float* tmp    = (float*)alloc(8192ULL * 1024 * 4);   // 33.6 MB

    bf16*  qkvb   = (bf16*)qkvreg;                       // [B,S,3E] bf16
    bf16*  attnb  = (bf16*)qkvreg;                       // aliases qkv (dead at PV time)
    bf16*  scoreb = (bf16*)R;                            // [B,H,S,S] bf16 (first half)
    bf16*  probs  = (bf16*)(R + 8192ULL * 4096);         // second half of R
    bf16*  vt     = (bf16*)R;                            // aliases scores (dead after softmax)
    bf16*  hbuf   = (bf16*)R;                            // FFN hidden, full R

    const dim3 blk(256);

    embed_kernel<<<8192, blk, 0, stream>>>(seq, temb, x, xb);

    for (int l = 0; l < 6; ++l) {
        cast_kernel<<<3072, blk, 0, stream>>>(Wqkv + (long)l * 3072 * 1024, wqkv_l, 786432);
        cast_kernel<<<1024, blk, 0, stream>>>(Wo   + (long)l * 1024 * 1024, wo_l,   262144);
        cast_kernel<<<4096, blk, 0, stream>>>(W1   + (long)l * 4096 * 1024, w1_l,  1048576);
        cast_kernel<<<4096, blk, 0, stream>>>(W2   + (long)l * 4096 * 1024, w2_l,  1048576);

        // QKV: [8192,1024] x [3072,1024]^T -> bf16 [8192,3072]
        gemm_bf16<<<dim3(64, 24, 1), blk, 0, stream>>>(xb, wqkv_l, qkvb,
            1024, 1024, 1024, 3072, 0, 0, 0, 0, 0, 0, 1,
            bqkv + (long)l * 3072, nullptr, 0.f, 1);

        // scores[b,h,q,k] = scale*(Q.K) + mask  (bf16)
        gemm_bf16<<<dim3(2, 2, 256), blk, 0, stream>>>(qkvb, qkvb + 1024, scoreb,
            128, 3072, 3072, 256,
            786432, 128, 786432, 128, 524288, 65536, 8,
            nullptr, demb, 0.08838834764831845f, 3);

        softmax_kernel<<<16384, blk, 0, stream>>>(scoreb, probs);
        transpose_v<<<dim3(32, 256), blk, 0, stream>>>(qkvb, vt);   // vt overwrites scores (dead)

        // O[b,q,h*128+d] = P.V  (attnb overwrites qkv region — Q,K,V all consumed)
        gemm_bf16<<<dim3(2, 1, 256), blk, 0, stream>>>(probs, vt, attnb,
            256, 256, 256, 1024,
            524288, 65536, 262144, 32768, 262144, 128, 8,
            nullptr, nullptr, 0.f, 1);

        // Wo: [8192,1024] x [1024,1024]^T -> f32 tmp
        gemm_bf16<<<dim3(64, 8, 1), blk, 0, stream>>>(attnb, wo_l, tmp,
            1024, 1024, 1024, 1024, 0, 0, 0, 0, 0, 0, 1,
            bo + (long)l * 1024, nullptr, 0.f, 0);

        ln_kernel<<<8192, blk, 0, stream>>>(x, tmp, ln1g + (long)l * 1024,
                                            ln1b + (long)l * 1024, x, xb, 1, 1);

        // FFN1 + GELU: [8192,1024] x [4096,1024]^T -> bf16 [8192,4096]
        gemm_bf16<<<dim3(64, 32, 1), blk, 0, stream>>>(xb, w1_l, hbuf,
            1024, 1024, 1024, 4096, 0, 0, 0, 0, 0, 0, 1,
            b1 + (long)l * 4096, nullptr, 0.f, 2);

        // FFN2: [8192,4096] x [1024,4096]^T -> f32 tmp
        gemm_bf16<<<dim3(64, 8, 1), blk, 0, stream>>>(hbuf, w2_l, tmp,
            4096, 4096, 4096, 1024, 0, 0, 0, 0, 0, 0, 1,
            b2 + (long)l * 1024, nullptr, 0.f, 0);

        ln_kernel<<<8192, blk, 0, stream>>>(x, tmp, ln2g + (long)l * 1024,
                                            ln2b + (long)l * 1024, x, xb, 1, 1);
    }

    // final LN (no residual) -> tmp (f32), then logits
    ln_kernel<<<8192, blk, 0, stream>>>(x, nullptr, fng, fnb, tmp, nullptr, 0, 0);
    gen_kernel<<<2048, blk, 0, stream>>>(tmp, genW, genb, out);
}

// Round 3
// 3118.243 us; speedup vs baseline: 1.1691x; 1.1691x over previous
//
#include <hip/hip_runtime.h>
#include <hip/hip_bf16.h>

typedef __hip_bfloat16 bf16;
typedef __attribute__((ext_vector_type(8))) short short8;
typedef __attribute__((ext_vector_type(4))) float f32x4;

#define GLB_AS(p) ((const __attribute__((address_space(1))) void*)(p))
#define LDS_AS(p) ((__attribute__((address_space(3))) void*)(p))

// ---------------------------------------------------------------------------
// Generic batched bf16 MFMA GEMM: C[m,n] = sum_k A[m,k]*B[n,k]  (+ epilogue)
// Tile: BM=BN=128, BK=64. Block=256 threads (4 waves, 2x2 of 64x64).
// LDS layout XOR-swizzled: 8-row x 64-col chunk, slot s of row r holds
// col-block s^r (s,r in 0..7, col-block = 8 bf16 = 16 B). Swizzle applied at
// the global fetch (global_load_lds dest is uniform-base + lane*16, fixed).
// EPI: 0 = +bias -> f32; 1 = +bias -> bf16; 2 = +bias,GELU -> bf16;
//      3 = *scale + dist/causal mask -> bf16 (attention scores)
// ---------------------------------------------------------------------------
template<int EPI>
__global__ __launch_bounds__(256) void gemm_bf16(
    const bf16* __restrict__ Ain, const bf16* __restrict__ Bin, void* __restrict__ Cv,
    int K, int lda, int ldb, int ldc,
    long sAo, long sAi, long sBo, long sBi, long sCo, long sCi, int nInner,
    const float* __restrict__ bias, const float* __restrict__ demb,
    float scale)
{
    __shared__ __align__(16) bf16 Als[128 * 64];
    __shared__ __align__(16) bf16 Bls[128 * 64];

    const int z  = blockIdx.z;
    const int zo = z / nInner;
    const int zi = z - zo * nInner;
    const bf16* A = Ain + zo * sAo + zi * sAi;
    const bf16* B = Bin + zo * sBo + zi * sBi;
    const long coff = zo * sCo + zi * sCi;

    // GROUP_M=8 supertile swizzle for L2 locality (x = M-tiles, y = N-tiles)
    const int Mt = gridDim.x, Nt = gridDim.y;
    int m_t, n_t;
    if (Mt >= 8) {
        const int pid = blockIdx.y * Mt + blockIdx.x;
        const int grpsz = 8 * Nt;
        const int grp = pid / grpsz;
        const int first = grp * 8;
        int rem = Mt - first; if (rem > 8) rem = 8;
        const int loc = pid - grp * grpsz;
        m_t = first + loc % rem;
        n_t = loc / rem;
    } else { m_t = blockIdx.x; n_t = blockIdx.y; }
    const int m0 = m_t * 128;
    const int n0 = n_t * 128;

    const int tid  = threadIdx.x;
    const int wave = tid >> 6;
    const int lane = tid & 63;
    const int wm = (wave >> 1) * 64;   // wave row offset in 128-tile
    const int wn = (wave & 1) * 64;    // wave col offset

    f32x4 acc[4][4];
#pragma unroll
    for (int i = 0; i < 4; ++i)
#pragma unroll
        for (int j = 0; j < 4; ++j) acc[i][j] = (f32x4){0.f, 0.f, 0.f, 0.f};

    // staging: each wave stages 4 chunks of 1KB for A and B.
    // chunk = 8 rows x 64 cols; lane i -> row i>>3, col-block (i&7)^(i>>3).
    const int srow = lane >> 3;                        // 0..7
    const int scol = (((lane & 7) ^ srow) << 3);       // XOR-swizzled col

    for (int k0 = 0; k0 < K; k0 += 64) {
        __syncthreads();   // protect LDS from previous iteration's readers
#pragma unroll
        for (int c = 0; c < 4; ++c) {
            const int chunk = (wave << 2) + c;
            const int row = (chunk << 3) + srow;
            const bf16* ga = A + (long)(m0 + row) * lda + k0 + scol;
            const bf16* gb = B + (long)(n0 + row) * ldb + k0 + scol;
            __builtin_amdgcn_global_load_lds(GLB_AS(ga), LDS_AS(&Als[chunk << 9]), 16, 0, 0);
            __builtin_amdgcn_global_load_lds(GLB_AS(gb), LDS_AS(&Bls[chunk << 9]), 16, 0, 0);
        }
        __syncthreads();   // drain global_load_lds (vmcnt) + visibility

#pragma unroll
        for (int kk = 0; kk < 2; ++kk) {
            const int CB = (kk << 2) + (lane >> 4);    // col-block 0..7
            const int r = lane & 15;
            short8 afr[4], bfr[4];
#pragma unroll
            for (int i = 0; i < 4; ++i) {
                const int ar = wm + (i << 4) + r;
                afr[i] = *(const short8*)&Als[ar * 64 + ((CB ^ (ar & 7)) << 3)];
            }
#pragma unroll
            for (int j = 0; j < 4; ++j) {
                const int br = wn + (j << 4) + r;
                bfr[j] = *(const short8*)&Bls[br * 64 + ((CB ^ (br & 7)) << 3)];
            }
#pragma unroll
            for (int i = 0; i < 4; ++i)
#pragma unroll
                for (int j = 0; j < 4; ++j)
                    acc[i][j] = __builtin_amdgcn_mfma_f32_16x16x32_bf16(
                        afr[i], bfr[j], acc[i][j], 0, 0, 0);
        }
    }

    // epilogue: C/D layout col=lane&15, row=(lane>>4)*4+reg
    const int ccol = lane & 15;
    const int crow = (lane >> 4) << 2;
#pragma unroll
    for (int i = 0; i < 4; ++i) {
#pragma unroll
        for (int j = 0; j < 4; ++j) {
            const int col  = n0 + wn + (j << 4) + ccol;
            const int rowb = m0 + wm + (i << 4) + crow;
#pragma unroll
            for (int r2 = 0; r2 < 4; ++r2) {
                const int row = rowb + r2;
                float v = acc[i][j][r2];
                const long cidx = coff + (long)row * ldc + col;
                if (EPI == 3) {
                    // scores: row = query q, col = key k (within batch)
                    int d0 = row - col;
                    int ad = d0 < 0 ? -d0 : d0;
                    if (ad > 250) ad = 250;
                    const float mb = (col <= row) ? demb[ad * 8 + zi] : -1e9f;
                    ((bf16*)Cv)[cidx] = __float2bfloat16(v * scale + mb);
                } else if (EPI == 0) {
                    if (bias) v += bias[col];
                    ((float*)Cv)[cidx] = v;
                } else if (EPI == 1) {
                    if (bias) v += bias[col];
                    ((bf16*)Cv)[cidx] = __float2bfloat16(v);
                } else {
                    v += bias[col];
                    v = 0.5f * v * (1.0f + erff(v * 0.70710678118f));
                    ((bf16*)Cv)[cidx] = __float2bfloat16(v);
                }
            }
        }
    }
}

// ---------------------------------------------------------------------------
// fp32 -> bf16 cast (vectorized, n4 = count/4)
// ---------------------------------------------------------------------------
__global__ void cast_kernel(const float* __restrict__ in, bf16* __restrict__ out, long n4)
{
    long i = (long)blockIdx.x * blockDim.x + threadIdx.x;
    if (i < n4) {
        f32x4 v = *(const f32x4*)(in + i * 4);
        bf16 t[4] = {__float2bfloat16(v[0]), __float2bfloat16(v[1]),
                     __float2bfloat16(v[2]), __float2bfloat16(v[3])};
        *(short4*)(out + i * 4) = *(const short4*)t;
    }
}

// ---------------------------------------------------------------------------
// embedding: x[t,:] = token_emb[seq[t]] * 32  (sqrt(1024)); writes f32 + bf16
// ---------------------------------------------------------------------------
__global__ void embed_kernel(const int* __restrict__ seq, const float* __restrict__ emb,
                             float* __restrict__ x, bf16* __restrict__ xb)
{
    const long t = blockIdx.x;
    const int tok = seq[t];
    const int tid = threadIdx.x;
    f32x4 v = *(const f32x4*)(emb + (long)tok * 1024 + tid * 4);
    v *= 32.0f;
    *(f32x4*)(x + t * 1024 + tid * 4) = v;
    bf16 tq[4] = {__float2bfloat16(v[0]), __float2bfloat16(v[1]),
                  __float2bfloat16(v[2]), __float2bfloat16(v[3])};
    *(short4*)(xb + t * 1024 + tid * 4) = *(const short4*)tq;
}

// ---------------------------------------------------------------------------
// softmax over rows of 256 (scores bf16 -> probs bf16). 1 wave/row.
// ---------------------------------------------------------------------------
__global__ void softmax_kernel(const bf16* __restrict__ scores, bf16* __restrict__ probs)
{
    const long row = (long)blockIdx.x * 4 + (threadIdx.x >> 6);
    const int lane = threadIdx.x & 63;
    short4 sv = *(const short4*)(scores + row * 256 + lane * 4);
    const bf16* sp = (const bf16*)&sv;
    float v0 = __bfloat162float(sp[0]), v1 = __bfloat162float(sp[1]);
    float v2 = __bfloat162float(sp[2]), v3 = __bfloat162float(sp[3]);
    float m = fmaxf(fmaxf(v0, v1), fmaxf(v2, v3));
#pragma unroll
    for (int off = 32; off; off >>= 1) m = fmaxf(m, __shfl_xor(m, off));
    float e0 = __expf(v0 - m), e1 = __expf(v1 - m);
    float e2 = __expf(v2 - m), e3 = __expf(v3 - m);
    float s = e0 + e1 + e2 + e3;
#pragma unroll
    for (int off = 32; off; off >>= 1) s += __shfl_xor(s, off);
    const float inv = 1.0f / s;
    bf16 tq[4] = {__float2bfloat16(e0 * inv), __float2bfloat16(e1 * inv),
                  __float2bfloat16(e2 * inv), __float2bfloat16(e3 * inv)};
    *(short4*)(probs + row * 256 + lane * 4) = *(const short4*)tq;
}

// ---------------------------------------------------------------------------
// V transpose: qkv[b,s,2E + h*128 + d] -> vt[b,h,d,s]  (bf16), LDS 32x33 tile
// ---------------------------------------------------------------------------
__global__ void transpose_v(const bf16* __restrict__ qkv, bf16* __restrict__ vt)
{
    __shared__ bf16 tile[32][33];
    const int bh = blockIdx.y;
    const int st = blockIdx.x & 7;
    const int dt = blockIdx.x >> 3;
    const int tx = threadIdx.x & 31;
    const int ty = threadIdx.x >> 5;   // 0..7
    const int b = bh >> 3, h = bh & 7;
    const bf16* src = qkv + ((long)b * 256) * 3072 + 2048 + h * 128 + dt * 32;
#pragma unroll
    for (int i = 0; i < 4; ++i) {
        const int s = st * 32 + ty * 4 + i;
        tile[ty * 4 + i][tx] = src[(long)s * 3072 + tx];
    }
    __syncthreads();
    bf16* dst = vt + ((long)bh * 128 + dt * 32) * 256 + st * 32;
#pragma unroll
    for (int i = 0; i < 4; ++i) {
        const int dl = ty * 4 + i;
        dst[(long)dl * 256 + tx] = tile[tx][dl];
    }
}

// ---------------------------------------------------------------------------
// LayerNorm over E=1024: out = (x [+ res] - mean)/sqrt(var+1e-5)*g + b
// ---------------------------------------------------------------------------
__global__ void ln_kernel(const float* __restrict__ x, const float* __restrict__ res,
                          const float* __restrict__ g, const float* __restrict__ bta,
                          float* __restrict__ outf, bf16* __restrict__ outb,
                          int has_res, int has_bf)
{
    const long t = blockIdx.x;
    const int tid = threadIdx.x;
    f32x4 v = *(const f32x4*)(x + t * 1024 + tid * 4);
    if (has_res) {
        f32x4 r = *(const f32x4*)(res + t * 1024 + tid * 4);
        v += r;
    }
    float s  = v[0] + v[1] + v[2] + v[3];
    float ss = v[0]*v[0] + v[1]*v[1] + v[2]*v[2] + v[3]*v[3];
#pragma unroll
    for (int off = 32; off; off >>= 1) {
        s  += __shfl_xor(s, off);
        ss += __shfl_xor(ss, off);
    }
    __shared__ float red[8];
    const int w = tid >> 6;
    if ((tid & 63) == 0) { red[w] = s; red[4 + w] = ss; }
    __syncthreads();
    s  = red[0] + red[1] + red[2] + red[3];
    ss = red[4] + red[5] + red[6] + red[7];
    const float mean = s * (1.0f / 1024.0f);
    const float var  = ss * (1.0f / 1024.0f) - mean * mean;
    const float rstd = rsqrtf(var + 1e-5f);
    f32x4 gv = *(const f32x4*)(g + tid * 4);
    f32x4 bv = *(const f32x4*)(bta + tid * 4);
    f32x4 o;
#pragma unroll
    for (int q = 0; q < 4; ++q) o[q] = (v[q] - mean) * rstd * gv[q] + bv[q];
    *(f32x4*)(outf + t * 1024 + tid * 4) = o;
    if (has_bf) {
        bf16 tq[4] = {__float2bfloat16(o[0]), __float2bfloat16(o[1]),
                      __float2bfloat16(o[2]), __float2bfloat16(o[3])};
        *(short4*)(outb + t * 1024 + tid * 4) = *(const short4*)tq;
    }
}

// ---------------------------------------------------------------------------
// logits: out[t,n] = xf[t,:].dot(W[n,:]) + b[n], N=45, K=1024 (fp32)
// ---------------------------------------------------------------------------
__global__ void gen_kernel(const float* __restrict__ xf, const float* __restrict__ W,
                           const float* __restrict__ bias, float* __restrict__ out)
{
    const long t = (long)blockIdx.x * 4 + (threadIdx.x >> 6);
    const int lane = threadIdx.x & 63;
    const float* xr = xf + t * 1024;
    float xv[16];
#pragma unroll
    for (int j = 0; j < 16; ++j) xv[j] = xr[lane + 64 * j];
    for (int n = 0; n < 45; ++n) {
        const float* wr = W + (long)n * 1024;
        float a = 0.f;
#pragma unroll
        for (int j = 0; j < 16; ++j) a += xv[j] * wr[lane + 64 * j];
#pragma unroll
        for (int off = 32; off; off >>= 1) a += __shfl_xor(a, off);
        if (lane == 0) out[t * 45 + n] = a + bias[n];
    }
}

// ---------------------------------------------------------------------------
extern "C" void kernel_launch(void* const* d_in, const int* in_sizes, int n_in,
                              void* d_out, int out_size, void* d_ws, size_t ws_size,
                              hipStream_t stream)
{
    (void)in_sizes; (void)n_in; (void)out_size; (void)ws_size;
    const int*   seq  = (const int*)d_in[0];
    const float* temb = (const float*)d_in[1];
    const float* demb = (const float*)d_in[2];
    const float* Wqkv = (const float*)d_in[3];
    const float* bqkv = (const float*)d_in[4];
    const float* Wo   = (const float*)d_in[5];
    const float* bo   = (const float*)d_in[6];
    const float* W1   = (const float*)d_in[7];
    const float* b1   = (const float*)d_in[8];
    const float* W2   = (const float*)d_in[9];
    const float* b2   = (const float*)d_in[10];
    const float* ln1g = (const float*)d_in[11];
    const float* ln1b = (const float*)d_in[12];
    const float* ln2g = (const float*)d_in[13];
    const float* ln2b = (const float*)d_in[14];
    const float* fng  = (const float*)d_in[15];
    const float* fnb  = (const float*)d_in[16];
    const float* genW = (const float*)d_in[17];
    const float* genb = (const float*)d_in[18];
    float* out = (float*)d_out;

    char* ws = (char*)d_ws;
    size_t off = 0;
    auto alloc = [&](size_t bytes) -> char* {
        char* p = ws + off;
        off += (bytes + 255) & ~(size_t)255;
        return p;
    };

    // Lifetime-aliased workspace (~226.5 MB total):
    bf16*  wqkv_l = (bf16*)alloc(3072ULL * 1024 * 2);    //  6.3 MB
    bf16*  wo_l   = (bf16*)alloc(1024ULL * 1024 * 2);    //  2.1 MB
    bf16*  w1_l   = (bf16*)alloc(4096ULL * 1024 * 2);    //  8.4 MB
    bf16*  w2_l   = (bf16*)alloc(1024ULL * 4096 * 2);    //  8.4 MB
    float* x      = (float*)alloc(8192ULL * 1024 * 4);   // 33.6 MB
    bf16*  xb     = (bf16*)alloc(8192ULL * 1024 * 2);    // 16.8 MB
    char*  qkvreg = alloc(8192ULL * 3072 * 2);           // 50.3 MB
    char*  R      = alloc(8192ULL * 4096 * 2);           // 67.1 MB
    float* tmp    = (float*)alloc(8192ULL * 1024 * 4);   // 33.6 MB

    bf16*  qkvb   = (bf16*)qkvreg;                       // [B,S,3E] bf16
    bf16*  attnb  = (bf16*)qkvreg;                       // aliases qkv (dead at PV time)
    bf16*  scoreb = (bf16*)R;                            // [B,H,S,S] bf16 (first half)
    bf16*  probs  = (bf16*)(R + 8192ULL * 4096);         // second half of R
    bf16*  vt     = (bf16*)R;                            // aliases scores (dead after softmax)
    bf16*  hbuf   = (bf16*)R;                            // FFN hidden, full R

    const dim3 blk(256);

    embed_kernel<<<8192, blk, 0, stream>>>(seq, temb, x, xb);

    for (int l = 0; l < 6; ++l) {
        cast_kernel<<<3072, blk, 0, stream>>>(Wqkv + (long)l * 3072 * 1024, wqkv_l, 786432);
        cast_kernel<<<1024, blk, 0, stream>>>(Wo   + (long)l * 1024 * 1024, wo_l,   262144);
        cast_kernel<<<4096, blk, 0, stream>>>(W1   + (long)l * 4096 * 1024, w1_l,  1048576);
        cast_kernel<<<4096, blk, 0, stream>>>(W2   + (long)l * 4096 * 1024, w2_l,  1048576);

        // QKV: [8192,1024] x [3072,1024]^T -> bf16 [8192,3072]
        gemm_bf16<1><<<dim3(64, 24, 1), blk, 0, stream>>>(xb, wqkv_l, qkvb,
            1024, 1024, 1024, 3072, 0, 0, 0, 0, 0, 0, 1,
            bqkv + (long)l * 3072, nullptr, 0.f);

        // scores[b,h,q,k] = scale*(Q.K) + mask  (bf16)
        gemm_bf16<3><<<dim3(2, 2, 256), blk, 0, stream>>>(qkvb, qkvb + 1024, scoreb,
            128, 3072, 3072, 256,
            786432, 128, 786432, 128, 524288, 65536, 8,
            nullptr, demb, 0.08838834764831845f);

        softmax_kernel<<<16384, blk, 0, stream>>>(scoreb, probs);
        transpose_v<<<dim3(32, 256), blk, 0, stream>>>(qkvb, vt);   // vt overwrites scores (dead)

        // O[b,q,h*128+d] = P.V  (attnb overwrites qkv region — Q,K,V consumed)
        gemm_bf16<1><<<dim3(2, 1, 256), blk, 0, stream>>>(probs, vt, attnb,
            256, 256, 256, 1024,
            524288, 65536, 262144, 32768, 262144, 128, 8,
            nullptr, nullptr, 0.f);

        // Wo: [8192,1024] x [1024,1024]^T -> f32 tmp
        gemm_bf16<0><<<dim3(64, 8, 1), blk, 0, stream>>>(attnb, wo_l, tmp,
            1024, 1024, 1024, 1024, 0, 0, 0, 0, 0, 0, 1,
            bo + (long)l * 1024, nullptr, 0.f);

        ln_kernel<<<8192, blk, 0, stream>>>(x, tmp, ln1g + (long)l * 1024,
                                            ln1b + (long)l * 1024, x, xb, 1, 1);

        // FFN1 + GELU: [8192,1024] x [4096,1024]^T -> bf16 [8192,4096]
        gemm_bf16<2><<<dim3(64, 32, 1), blk, 0, stream>>>(xb, w1_l, hbuf,
            1024, 1024, 1024, 4096, 0, 0, 0, 0, 0, 0, 1,
            b1 + (long)l * 4096, nullptr, 0.f);

        // FFN2: [8192,4096] x [1024,4096]^T -> f32 tmp
        gemm_bf16<0><<<dim3(64, 8, 1), blk, 0, stream>>>(hbuf, w2_l, tmp,
            4096, 4096, 4096, 1024, 0, 0, 0, 0, 0, 0, 1,
            b2 + (long)l * 1024, nullptr, 0.f);

        ln_kernel<<<8192, blk, 0, stream>>>(x, tmp, ln2g + (long)l * 1024,
                                            ln2b + (long)l * 1024, x, xb, 1, 1);
    }

    // final LN (no residual) -> tmp (f32), then logits
    ln_kernel<<<8192, blk, 0, stream>>>(x, nullptr, fng, fnb, tmp, nullptr, 0, 0);
    gen_kernel<<<2048, blk, 0, stream>>>(tmp, genW, genb, out);
}

// Round 5
// 2872.929 us; speedup vs baseline: 1.2689x; 1.0854x over previous
//
#include <hip/hip_runtime.h>
#include <hip/hip_bf16.h>

typedef __hip_bfloat16 bf16;
typedef __attribute__((ext_vector_type(8))) short short8;
typedef __attribute__((ext_vector_type(4))) float f32x4;

#define GLB_AS(p) ((const __attribute__((address_space(1))) void*)(p))
#define LDS_AS(p) ((__attribute__((address_space(3))) void*)(p))

// ---------------------------------------------------------------------------
// Generic batched bf16 MFMA GEMM: C[m,n] = sum_k A[m,k]*B[n,k]  (+ epilogue)
// Tile: BM=BN=128, BK=64. Block=256 threads (4 waves, 2x2 of 64x64).
// LDS XOR-swizzled (slot s of row r holds col-block s^r) -> 0 bank conflicts.
// EPI: 0 = +bias -> f32; 1 = +bias -> bf16; 2 = +bias,GELU -> bf16;
//      3 = *scale + dist bias -> bf16 scores; causal tile remap:
//          blockIdx.x in {0,1,2} -> (m_t,n_t) = (0,0),(1,0),(1,1)
//          (fully-masked tile (0,1) never written; softmax is causal-aware
//           and never reads it)
//      4 = bf16 out, causal PV: K_eff = (m_t+1)*128 (probs are exactly 0
//          beyond the causal limit because softmax zeroes them)
// ---------------------------------------------------------------------------
template<int EPI>
__global__ __launch_bounds__(256) void gemm_bf16(
    const bf16* __restrict__ Ain, const bf16* __restrict__ Bin, void* __restrict__ Cv,
    int K, int lda, int ldb, int ldc,
    long sAo, long sAi, long sBo, long sBi, long sCo, long sCi, int nInner,
    const float* __restrict__ bias, const float* __restrict__ demb,
    float scale)
{
    __shared__ __align__(16) bf16 Als[128 * 64];
    __shared__ __align__(16) bf16 Bls[128 * 64];

    const int z  = blockIdx.z;
    const int zo = z / nInner;
    const int zi = z - zo * nInner;
    const bf16* A = Ain + zo * sAo + zi * sAi;
    const bf16* B = Bin + zo * sBo + zi * sBi;
    const long coff = zo * sCo + zi * sCi;

    int m_t, n_t;
    if (EPI == 3) {
        // causal tile remap: only lower-triangular 128-tiles
        m_t = (blockIdx.x + 1) >> 1;   // 0,1,1
        n_t = blockIdx.x >> 1;         // 0,0,1
    } else {
        // GROUP_M=8 supertile swizzle for L2 locality
        const int Mt = gridDim.x, Nt = gridDim.y;
        if (Mt >= 8) {
            const int pid = blockIdx.y * Mt + blockIdx.x;
            const int grpsz = 8 * Nt;
            const int grp = pid / grpsz;
            const int first = grp * 8;
            int rem = Mt - first; if (rem > 8) rem = 8;
            const int loc = pid - grp * grpsz;
            m_t = first + loc % rem;
            n_t = loc / rem;
        } else { m_t = blockIdx.x; n_t = blockIdx.y; }
    }
    const int m0 = m_t * 128;
    const int n0 = n_t * 128;

    const int Keff = (EPI == 4) ? (m_t + 1) * 128 : K;

    const int tid  = threadIdx.x;
    const int wave = tid >> 6;
    const int lane = tid & 63;
    const int wm = (wave >> 1) * 64;   // wave row offset in 128-tile
    const int wn = (wave & 1) * 64;    // wave col offset

    f32x4 acc[4][4];
#pragma unroll
    for (int i = 0; i < 4; ++i)
#pragma unroll
        for (int j = 0; j < 4; ++j) acc[i][j] = (f32x4){0.f, 0.f, 0.f, 0.f};

    // staging: chunk = 8 rows x 64 cols; lane i -> row i>>3, col-block (i&7)^(i>>3)
    const int srow = lane >> 3;                        // 0..7
    const int scol = (((lane & 7) ^ srow) << 3);       // XOR-swizzled col

    for (int k0 = 0; k0 < Keff; k0 += 64) {
        __syncthreads();   // protect LDS from previous iteration's readers
#pragma unroll
        for (int c = 0; c < 4; ++c) {
            const int chunk = (wave << 2) + c;
            const int row = (chunk << 3) + srow;
            const bf16* ga = A + (long)(m0 + row) * lda + k0 + scol;
            const bf16* gb = B + (long)(n0 + row) * ldb + k0 + scol;
            __builtin_amdgcn_global_load_lds(GLB_AS(ga), LDS_AS(&Als[chunk << 9]), 16, 0, 0);
            __builtin_amdgcn_global_load_lds(GLB_AS(gb), LDS_AS(&Bls[chunk << 9]), 16, 0, 0);
        }
        __syncthreads();   // drain global_load_lds (vmcnt) + visibility

#pragma unroll
        for (int kk = 0; kk < 2; ++kk) {
            const int CB = (kk << 2) + (lane >> 4);    // col-block 0..7
            const int r = lane & 15;
            short8 afr[4], bfr[4];
#pragma unroll
            for (int i = 0; i < 4; ++i) {
                const int ar = wm + (i << 4) + r;
                afr[i] = *(const short8*)&Als[ar * 64 + ((CB ^ (ar & 7)) << 3)];
            }
#pragma unroll
            for (int j = 0; j < 4; ++j) {
                const int br = wn + (j << 4) + r;
                bfr[j] = *(const short8*)&Bls[br * 64 + ((CB ^ (br & 7)) << 3)];
            }
#pragma unroll
            for (int i = 0; i < 4; ++i)
#pragma unroll
                for (int j = 0; j < 4; ++j)
                    acc[i][j] = __builtin_amdgcn_mfma_f32_16x16x32_bf16(
                        afr[i], bfr[j], acc[i][j], 0, 0, 0);
        }
    }

    // epilogue: C/D layout col=lane&15, row=(lane>>4)*4+reg
    const int ccol = lane & 15;
    const int crow = (lane >> 4) << 2;
#pragma unroll
    for (int i = 0; i < 4; ++i) {
#pragma unroll
        for (int j = 0; j < 4; ++j) {
            const int col  = n0 + wn + (j << 4) + ccol;
            const int rowb = m0 + wm + (i << 4) + crow;
#pragma unroll
            for (int r2 = 0; r2 < 4; ++r2) {
                const int row = rowb + r2;
                float v = acc[i][j][r2];
                const long cidx = coff + (long)row * ldc + col;
                if (EPI == 3) {
                    int d0 = row - col;
                    int ad = d0 < 0 ? -d0 : d0;
                    if (ad > 250) ad = 250;
                    // causal masking handled in softmax; just add dist bias
                    ((bf16*)Cv)[cidx] = __float2bfloat16(v * scale + demb[ad * 8 + zi]);
                } else if (EPI == 0) {
                    if (bias) v += bias[col];
                    ((float*)Cv)[cidx] = v;
                } else if (EPI == 1 || EPI == 4) {
                    if (bias) v += bias[col];
                    ((bf16*)Cv)[cidx] = __float2bfloat16(v);
                } else {
                    v += bias[col];
                    v = 0.5f * v * (1.0f + erff(v * 0.70710678118f));
                    ((bf16*)Cv)[cidx] = __float2bfloat16(v);
                }
            }
        }
    }
}

// ---------------------------------------------------------------------------
// merged fp32 -> bf16 cast over 4 weight arrays (counts in 4-elem groups)
// ---------------------------------------------------------------------------
__global__ void cast4_kernel(const float* __restrict__ s0, const float* __restrict__ s1,
                             const float* __restrict__ s2, const float* __restrict__ s3,
                             bf16* __restrict__ d0, bf16* __restrict__ d1,
                             bf16* __restrict__ d2, bf16* __restrict__ d3,
                             long n0, long n1, long n2, long n3)
{
    long i = (long)blockIdx.x * blockDim.x + threadIdx.x;
    const float* s; bf16* d; long base;
    if (i < n0)                { s = s0; d = d0; base = 0; }
    else if (i < n0 + n1)      { s = s1; d = d1; base = n0; }
    else if (i < n0 + n1 + n2) { s = s2; d = d2; base = n0 + n1; }
    else if (i < n0+n1+n2+n3)  { s = s3; d = d3; base = n0 + n1 + n2; }
    else return;
    const long j = i - base;
    f32x4 v = *(const f32x4*)(s + j * 4);
    bf16 t[4] = {__float2bfloat16(v[0]), __float2bfloat16(v[1]),
                 __float2bfloat16(v[2]), __float2bfloat16(v[3])};
    *(short4*)(d + j * 4) = *(const short4*)t;
}

// ---------------------------------------------------------------------------
// embedding: x[t,:] = token_emb[seq[t]] * 32  (sqrt(1024)); writes f32 + bf16
// ---------------------------------------------------------------------------
__global__ void embed_kernel(const int* __restrict__ seq, const float* __restrict__ emb,
                             float* __restrict__ x, bf16* __restrict__ xb)
{
    const long t = blockIdx.x;
    const int tok = seq[t];
    const int tid = threadIdx.x;
    f32x4 v = *(const f32x4*)(emb + (long)tok * 1024 + tid * 4);
    v *= 32.0f;
    *(f32x4*)(x + t * 1024 + tid * 4) = v;
    bf16 tq[4] = {__float2bfloat16(v[0]), __float2bfloat16(v[1]),
                  __float2bfloat16(v[2]), __float2bfloat16(v[3])};
    *(short4*)(xb + t * 1024 + tid * 4) = *(const short4*)tq;
}

// ---------------------------------------------------------------------------
// Causal softmax over rows of 256 (scores bf16 -> probs bf16). 1 wave/row.
// Row's query index q = row & 255; keys k > q are excluded (prob = 0).
// Never reads the unwritten fully-masked score tile (k>=128 when q<128 is
// loaded but discarded by the causal predicate).
// ---------------------------------------------------------------------------
__global__ void softmax_kernel(const bf16* __restrict__ scores, bf16* __restrict__ probs)
{
    const long row = (long)blockIdx.x * 4 + (threadIdx.x >> 6);
    const int q = (int)(row & 255);
    const int lane = threadIdx.x & 63;
    const int kbase = lane * 4;
    short4 sv = *(const short4*)(scores + row * 256 + kbase);
    const bf16* sp = (const bf16*)&sv;
    float v0 = (kbase + 0 <= q) ? __bfloat162float(sp[0]) : -1e30f;
    float v1 = (kbase + 1 <= q) ? __bfloat162float(sp[1]) : -1e30f;
    float v2 = (kbase + 2 <= q) ? __bfloat162float(sp[2]) : -1e30f;
    float v3 = (kbase + 3 <= q) ? __bfloat162float(sp[3]) : -1e30f;
    float m = fmaxf(fmaxf(v0, v1), fmaxf(v2, v3));
#pragma unroll
    for (int off = 32; off; off >>= 1) m = fmaxf(m, __shfl_xor(m, off));
    float e0 = (kbase + 0 <= q) ? __expf(v0 - m) : 0.f;
    float e1 = (kbase + 1 <= q) ? __expf(v1 - m) : 0.f;
    float e2 = (kbase + 2 <= q) ? __expf(v2 - m) : 0.f;
    float e3 = (kbase + 3 <= q) ? __expf(v3 - m) : 0.f;
    float s = e0 + e1 + e2 + e3;
#pragma unroll
    for (int off = 32; off; off >>= 1) s += __shfl_xor(s, off);
    const float inv = 1.0f / s;
    bf16 tq[4] = {__float2bfloat16(e0 * inv), __float2bfloat16(e1 * inv),
                  __float2bfloat16(e2 * inv), __float2bfloat16(e3 * inv)};
    *(short4*)(probs + row * 256 + kbase) = *(const short4*)tq;
}

// ---------------------------------------------------------------------------
// V transpose: qkv[b,s,2E + h*128 + d] -> vt[b,h,d,s]  (bf16), LDS 32x33 tile
// ---------------------------------------------------------------------------
__global__ void transpose_v(const bf16* __restrict__ qkv, bf16* __restrict__ vt)
{
    __shared__ bf16 tile[32][33];
    const int bh = blockIdx.y;
    const int st = blockIdx.x & 7;
    const int dt = blockIdx.x >> 3;
    const int tx = threadIdx.x & 31;
    const int ty = threadIdx.x >> 5;   // 0..7
    const int b = bh >> 3, h = bh & 7;
    const bf16* src = qkv + ((long)b * 256) * 3072 + 2048 + h * 128 + dt * 32;
#pragma unroll
    for (int i = 0; i < 4; ++i) {
        const int s = st * 32 + ty * 4 + i;
        tile[ty * 4 + i][tx] = src[(long)s * 3072 + tx];
    }
    __syncthreads();
    bf16* dst = vt + ((long)bh * 128 + dt * 32) * 256 + st * 32;
#pragma unroll
    for (int i = 0; i < 4; ++i) {
        const int dl = ty * 4 + i;
        dst[(long)dl * 256 + tx] = tile[tx][dl];
    }
}

// ---------------------------------------------------------------------------
// LayerNorm over E=1024: out = (x [+ res(bf16)] - mean)/sqrt(var+1e-5)*g + b
// ---------------------------------------------------------------------------
__global__ void ln_kernel(const float* __restrict__ x, const bf16* __restrict__ res,
                          const float* __restrict__ g, const float* __restrict__ bta,
                          float* __restrict__ outf, bf16* __restrict__ outb,
                          int has_res, int has_bf)
{
    const long t = blockIdx.x;
    const int tid = threadIdx.x;
    f32x4 v = *(const f32x4*)(x + t * 1024 + tid * 4);
    if (has_res) {
        short4 rv = *(const short4*)(res + t * 1024 + tid * 4);
        const bf16* rp = (const bf16*)&rv;
#pragma unroll
        for (int q = 0; q < 4; ++q) v[q] += __bfloat162float(rp[q]);
    }
    float s  = v[0] + v[1] + v[2] + v[3];
    float ss = v[0]*v[0] + v[1]*v[1] + v[2]*v[2] + v[3]*v[3];
#pragma unroll
    for (int off = 32; off; off >>= 1) {
        s  += __shfl_xor(s, off);
        ss += __shfl_xor(ss, off);
    }
    __shared__ float red[8];
    const int w = tid >> 6;
    if ((tid & 63) == 0) { red[w] = s; red[4 + w] = ss; }
    __syncthreads();
    s  = red[0] + red[1] + red[2] + red[3];
    ss = red[4] + red[5] + red[6] + red[7];
    const float mean = s * (1.0f / 1024.0f);
    const float var  = ss * (1.0f / 1024.0f) - mean * mean;
    const float rstd = rsqrtf(var + 1e-5f);
    f32x4 gv = *(const f32x4*)(g + tid * 4);
    f32x4 bv = *(const f32x4*)(bta + tid * 4);
    f32x4 o;
#pragma unroll
    for (int q = 0; q < 4; ++q) o[q] = (v[q] - mean) * rstd * gv[q] + bv[q];
    *(f32x4*)(outf + t * 1024 + tid * 4) = o;
    if (has_bf) {
        bf16 tq[4] = {__float2bfloat16(o[0]), __float2bfloat16(o[1]),
                      __float2bfloat16(o[2]), __float2bfloat16(o[3])};
        *(short4*)(outb + t * 1024 + tid * 4) = *(const short4*)tq;
    }
}

// ---------------------------------------------------------------------------
// logits: out[t,n] = xf[t,:].dot(W[n,:]) + b[n], N=45, K=1024 (fp32)
// ---------------------------------------------------------------------------
__global__ void gen_kernel(const float* __restrict__ xf, const float* __restrict__ W,
                           const float* __restrict__ bias, float* __restrict__ out)
{
    const long t = (long)blockIdx.x * 4 + (threadIdx.x >> 6);
    const int lane = threadIdx.x & 63;
    const float* xr = xf + t * 1024;
    float xv[16];
#pragma unroll
    for (int j = 0; j < 16; ++j) xv[j] = xr[lane + 64 * j];
    for (int n = 0; n < 45; ++n) {
        const float* wr = W + (long)n * 1024;
        float a = 0.f;
#pragma unroll
        for (int j = 0; j < 16; ++j) a += xv[j] * wr[lane + 64 * j];
#pragma unroll
        for (int off = 32; off; off >>= 1) a += __shfl_xor(a, off);
        if (lane == 0) out[t * 45 + n] = a + bias[n];
    }
}

// ---------------------------------------------------------------------------
extern "C" void kernel_launch(void* const* d_in, const int* in_sizes, int n_in,
                              void* d_out, int out_size, void* d_ws, size_t ws_size,
                              hipStream_t stream)
{
    (void)in_sizes; (void)n_in; (void)out_size; (void)ws_size;
    const int*   seq  = (const int*)d_in[0];
    const float* temb = (const float*)d_in[1];
    const float* demb = (const float*)d_in[2];
    const float* Wqkv = (const float*)d_in[3];
    const float* bqkv = (const float*)d_in[4];
    const float* Wo   = (const float*)d_in[5];
    const float* bo   = (const float*)d_in[6];
    const float* W1   = (const float*)d_in[7];
    const float* b1   = (const float*)d_in[8];
    const float* W2   = (const float*)d_in[9];
    const float* b2   = (const float*)d_in[10];
    const float* ln1g = (const float*)d_in[11];
    const float* ln1b = (const float*)d_in[12];
    const float* ln2g = (const float*)d_in[13];
    const float* ln2b = (const float*)d_in[14];
    const float* fng  = (const float*)d_in[15];
    const float* fnb  = (const float*)d_in[16];
    const float* genW = (const float*)d_in[17];
    const float* genb = (const float*)d_in[18];
    float* out = (float*)d_out;

    char* ws = (char*)d_ws;
    size_t off = 0;
    auto alloc = [&](size_t bytes) -> char* {
        char* p = ws + off;
        off += (bytes + 255) & ~(size_t)255;
        return p;
    };

    // Lifetime-aliased workspace (~210 MB total):
    bf16*  wqkv_l = (bf16*)alloc(3072ULL * 1024 * 2);    //  6.3 MB
    bf16*  wo_l   = (bf16*)alloc(1024ULL * 1024 * 2);    //  2.1 MB
    bf16*  w1_l   = (bf16*)alloc(4096ULL * 1024 * 2);    //  8.4 MB
    bf16*  w2_l   = (bf16*)alloc(1024ULL * 4096 * 2);    //  8.4 MB
    float* x      = (float*)alloc(8192ULL * 1024 * 4);   // 33.6 MB
    bf16*  xb     = (bf16*)alloc(8192ULL * 1024 * 2);    // 16.8 MB
    char*  qkvreg = alloc(8192ULL * 3072 * 2);           // 50.3 MB
    char*  R      = alloc(8192ULL * 4096 * 2);           // 67.1 MB
    bf16*  tmpb   = (bf16*)alloc(8192ULL * 1024 * 2);    // 16.8 MB

    bf16*  qkvb   = (bf16*)qkvreg;                       // [B,S,3E] bf16
    bf16*  attnb  = (bf16*)qkvreg;                       // aliases qkv (dead at PV time)
    float* lnout  = (float*)qkvreg;                      // final-LN f32 (end only)
    bf16*  scoreb = (bf16*)R;                            // [B,H,S,S] bf16 (first half)
    bf16*  probs  = (bf16*)(R + 8192ULL * 4096);         // second half of R
    bf16*  vt     = (bf16*)R;                            // aliases scores (dead after softmax)
    bf16*  hbuf   = (bf16*)R;                            // FFN hidden, full R

    const dim3 blk(256);

    embed_kernel<<<8192, blk, 0, stream>>>(seq, temb, x, xb);

    for (int l = 0; l < 6; ++l) {
        cast4_kernel<<<12288, blk, 0, stream>>>(
            Wqkv + (long)l * 3072 * 1024, Wo + (long)l * 1024 * 1024,
            W1 + (long)l * 4096 * 1024,   W2 + (long)l * 4096 * 1024,
            wqkv_l, wo_l, w1_l, w2_l,
            786432, 262144, 1048576, 1048576);

        // QKV: [8192,1024] x [3072,1024]^T -> bf16 [8192,3072]
        gemm_bf16<1><<<dim3(64, 24, 1), blk, 0, stream>>>(xb, wqkv_l, qkvb,
            1024, 1024, 1024, 3072, 0, 0, 0, 0, 0, 0, 1,
            bqkv + (long)l * 3072, nullptr, 0.f);

        // scores[b,h,q,k] = scale*(Q.K) + dist bias (bf16); 3 causal tiles only
        gemm_bf16<3><<<dim3(3, 1, 256), blk, 0, stream>>>(qkvb, qkvb + 1024, scoreb,
            128, 3072, 3072, 256,
            786432, 128, 786432, 128, 524288, 65536, 8,
            nullptr, demb, 0.08838834764831845f);

        softmax_kernel<<<16384, blk, 0, stream>>>(scoreb, probs);
        transpose_v<<<dim3(32, 256), blk, 0, stream>>>(qkvb, vt);   // vt overwrites scores (dead)

        // O[b,q,h*128+d] = P.V ; causal K-limit per q-tile
        gemm_bf16<4><<<dim3(2, 1, 256), blk, 0, stream>>>(probs, vt, attnb,
            256, 256, 256, 1024,
            524288, 65536, 262144, 32768, 262144, 128, 8,
            nullptr, nullptr, 0.f);

        // Wo: [8192,1024] x [1024,1024]^T -> bf16 tmpb
        gemm_bf16<1><<<dim3(64, 8, 1), blk, 0, stream>>>(attnb, wo_l, tmpb,
            1024, 1024, 1024, 1024, 0, 0, 0, 0, 0, 0, 1,
            bo + (long)l * 1024, nullptr, 0.f);

        ln_kernel<<<8192, blk, 0, stream>>>(x, tmpb, ln1g + (long)l * 1024,
                                            ln1b + (long)l * 1024, x, xb, 1, 1);

        // FFN1 + GELU: [8192,1024] x [4096,1024]^T -> bf16 [8192,4096]
        gemm_bf16<2><<<dim3(64, 32, 1), blk, 0, stream>>>(xb, w1_l, hbuf,
            1024, 1024, 1024, 4096, 0, 0, 0, 0, 0, 0, 1,
            b1 + (long)l * 4096, nullptr, 0.f);

        // FFN2: [8192,4096] x [1024,4096]^T -> bf16 tmpb
        gemm_bf16<1><<<dim3(64, 8, 1), blk, 0, stream>>>(hbuf, w2_l, tmpb,
            4096, 4096, 4096, 1024, 0, 0, 0, 0, 0, 0, 1,
            b2 + (long)l * 1024, nullptr, 0.f);

        ln_kernel<<<8192, blk, 0, stream>>>(x, tmpb, ln2g + (long)l * 1024,
                                            ln2b + (long)l * 1024, x, xb, 1, 1);
    }

    // final LN (no residual) -> lnout (f32), then logits
    ln_kernel<<<8192, blk, 0, stream>>>(x, nullptr, fng, fnb, lnout, nullptr, 0, 0);
    gen_kernel<<<2048, blk, 0, stream>>>(lnout, genW, genb, out);
}